// Round 8
// baseline (90.947 us; speedup 1.0000x reference)
//
#include <hip/hip_runtime.h>

typedef __attribute__((ext_vector_type(8))) short bf16x8;
typedef __attribute__((ext_vector_type(16))) float f32x16;
typedef __attribute__((ext_vector_type(4))) unsigned uint4v;
typedef __attribute__((ext_vector_type(2))) unsigned uint2v;

#define MFMA32(a, b, c) __builtin_amdgcn_mfma_f32_32x32x16_bf16((a), (b), (c), 0, 0, 0)

__device__ __forceinline__ unsigned pk2(float lo, float hi) {
  unsigned r;
  asm("v_cvt_pk_bf16_f32 %0, %1, %2" : "=v"(r) : "v"(lo), "v"(hi));
  return r;
}

__device__ __forceinline__ float fexp2(float x) {
  float y; asm("v_exp_f32 %0, %1" : "=v"(y) : "v"(x)); return y;
}

__device__ __forceinline__ f32x16 zero16() {
  f32x16 z;
#pragma unroll
  for (int i = 0; i < 16; ++i) z[i] = 0.0f;
  return z;
}

constexpr int S_ = 1024, D = 128;
constexpr int QSTR = 32 * 128;  // query/out row stride (floats)
constexpr int KSTR = 8 * 128;   // key/value row stride (floats)
// log2(e)/sqrt(128): scores computed directly in log2 domain
constexpr float QSCL = 0.12751741f;

// grid = 512, block = 512 (8 waves). bid -> (hkv, b, qt64) EXACTLY as the
// 63.6us R4 kernel (proven best L3 locality + dispatch order; R5/R6/R7
// balance attempts all regressed). R8 change: KVBLK 64 -> 128. Residency is
// register-pinned at 1 block/CU (2 waves/SIMD), so the per-tile FIXED costs
// (barrier, max-tree+shfl+any, rescale, loop/addr, staging pack) dominate
// (~780 VALU vs 32 MFMA per wave-tile). Doubling the kv tile amortizes them
// 2x: half the barriers/softmax events, 64-MFMA bursts. LDS 128KB dbuf is
// free at 1 block/CU. A-frags kept transient by fusing pack->PV per 32-kv.
__global__ __launch_bounds__(512, 2) void fa_kernel(
    const float* __restrict__ Qg, const float* __restrict__ Kg,
    const float* __restrict__ Vg, float* __restrict__ Og) {
  const int bid  = blockIdx.x;
  const int hkv  = bid & 7;
  const int b    = (bid >> 3) & 3;
  const int qt64 = 15 - (bid >> 5);   // 0..15, heaviest dispatched first
  const int h4   = hkv << 2;

  const int tid  = threadIdx.x;
  const int wid  = tid >> 6;          // 0..7
  const int lane = tid & 63;
  const int r    = lane & 31;
  const int hi   = lane >> 5;

  const int g     = wid & 3;
  const int strip = wid >> 2;
  const int h     = h4 + g;
  const int wq0   = (qt64 << 6) + (strip << 5);
  const int qrow  = wq0 + r;

  // K: [128 kv][128 bf16] rows of 256B = 16 slots, slot ^= (row&7)
  // V: transposed [128 d][128 bf16(kv)] rows of 256B = 16 slots, slot ^= (d&7)
  __shared__ __align__(16) unsigned char Kl0[128 * 256];
  __shared__ __align__(16) unsigned char Vl0[128 * 256];
  __shared__ __align__(16) unsigned char Kl1[128 * 256];
  __shared__ __align__(16) unsigned char Vl1[128 * 256];

  // ---- Q fragments (pre-scaled into log2 domain) ----
  bf16x8 qf[8];
  {
    const float* qp = Qg + (size_t)(b * S_ + qrow) * QSTR + h * D;
#pragma unroll
    for (int c = 0; c < 8; ++c) {
      const float4* p4 = (const float4*)(qp + 16 * c + 8 * hi);
      float4 x = p4[0], y = p4[1];
      uint4v w = (uint4v){pk2(x.x * QSCL, x.y * QSCL), pk2(x.z * QSCL, x.w * QSCL),
                          pk2(y.x * QSCL, y.y * QSCL), pk2(y.z * QSCL, y.w * QSCL)};
      qf[c] = __builtin_bit_cast(bf16x8, w);
    }
  }

  // ---- prefetch registers + stage mapping (512 threads, 128-kv tile) ----
  const int kvrow = tid >> 2;            // K: 4 threads per kv row (128 rows)
  const int dbase = (tid & 3) << 5;      // 32 floats each
  const float* kbase = Kg + (size_t)(b * S_) * KSTR + hkv * D;
  const int vd   = tid & 127;            // V: d index 0..127
  const int vkvb = (tid >> 7) << 5;      // kv sub-block 0/32/64/96
  const float* vbase = Vg + (size_t)(b * S_) * KSTR + hkv * D;

  float4 kreg[8];
  float  vreg[32];

  auto ISSUE = [&](int kv0) {
    const float4* kp = (const float4*)(kbase + (size_t)(kv0 + kvrow) * KSTR + dbase);
#pragma unroll
    for (int j = 0; j < 8; ++j) kreg[j] = kp[j];
    const float* vp = vbase + (size_t)(kv0 + vkvb) * KSTR + vd;
#pragma unroll
    for (int kk = 0; kk < 32; ++kk) vreg[kk] = vp[kk * KSTR];
  };

  auto WRITE = [&](unsigned char* Kl, unsigned char* Vl) {
#pragma unroll
    for (int ss = 0; ss < 4; ++ss) {
      float4 x = kreg[2 * ss], y = kreg[2 * ss + 1];
      uint4v w = (uint4v){pk2(x.x, x.y), pk2(x.z, x.w), pk2(y.x, y.y), pk2(y.z, y.w)};
      const int slot = (dbase >> 3) + ss;   // 4*(tid&3)+ss -> 0..15
      *(uint4v*)(Kl + kvrow * 256 + ((slot ^ (kvrow & 7)) << 4)) = w;
    }
#pragma unroll
    for (int ss = 0; ss < 4; ++ss) {
      uint4v w = (uint4v){pk2(vreg[8 * ss + 0], vreg[8 * ss + 1]),
                          pk2(vreg[8 * ss + 2], vreg[8 * ss + 3]),
                          pk2(vreg[8 * ss + 4], vreg[8 * ss + 5]),
                          pk2(vreg[8 * ss + 6], vreg[8 * ss + 7])};
      const int slot = (vkvb >> 3) + ss;    // 4*(tid>>7)+ss -> 0..15
      *(uint4v*)(Vl + vd * 256 + ((slot ^ (vd & 7)) << 4)) = w;
    }
  };

  f32x16 o0 = zero16(), o1 = zero16(), o2 = zero16(), o3 = zero16();
  float m = -1e30f, lsum = 0.0f;

  // pack one 32-kv score block -> 2 A-frags -> immediately PV-accumulate
  // (A-frags transient: only 8 regs live). t2 = kv chunk index (2j).
  auto PACKPV = [&](const unsigned char* Vl, const f32x16& sj, int t2) {
    float p[16];
#pragma unroll
    for (int rr = 0; rr < 16; ++rr) p[rr] = fexp2(sj[rr] - m);
    float pa = 0.0f, pb = 0.0f, pc = 0.0f, pd = 0.0f;
#pragma unroll
    for (int rr = 0; rr < 4; ++rr) {
      pa += p[4 * rr + 0]; pb += p[4 * rr + 1];
      pc += p[4 * rr + 2]; pd += p[4 * rr + 3];
    }
    lsum += (pa + pb) + (pc + pd);
    unsigned d0 = pk2(p[0], p[1]),   d1 = pk2(p[2], p[3]);
    unsigned d2 = pk2(p[4], p[5]),   d3 = pk2(p[6], p[7]);
    unsigned d4 = pk2(p[8], p[9]),   d5 = pk2(p[10], p[11]);
    unsigned d6 = pk2(p[12], p[13]), d7 = pk2(p[14], p[15]);
    uint2v w02 = __builtin_amdgcn_permlane32_swap(d0, d2, false, false);
    uint2v w13 = __builtin_amdgcn_permlane32_swap(d1, d3, false, false);
    uint2v w46 = __builtin_amdgcn_permlane32_swap(d4, d6, false, false);
    uint2v w57 = __builtin_amdgcn_permlane32_swap(d5, d7, false, false);
    bf16x8 Aa = __builtin_bit_cast(bf16x8, (uint4v){w02[0], w13[0], w02[1], w13[1]});
    bf16x8 Ab = __builtin_bit_cast(bf16x8, (uint4v){w46[0], w57[0], w46[1], w57[1]});
    __builtin_amdgcn_s_setprio(1);
    {
      const int so = (((2 * t2 + hi) ^ (r & 7)) << 4);
      bf16x8 v0 = *(const bf16x8*)(Vl + r * 256 + so);
      bf16x8 v1 = *(const bf16x8*)(Vl + (32 + r) * 256 + so);
      bf16x8 v2 = *(const bf16x8*)(Vl + (64 + r) * 256 + so);
      bf16x8 v3 = *(const bf16x8*)(Vl + (96 + r) * 256 + so);
      o0 = MFMA32(Aa, v0, o0);
      o1 = MFMA32(Aa, v1, o1);
      o2 = MFMA32(Aa, v2, o2);
      o3 = MFMA32(Aa, v3, o3);
    }
    {
      const int so = (((2 * (t2 + 1) + hi) ^ (r & 7)) << 4);
      bf16x8 v0 = *(const bf16x8*)(Vl + r * 256 + so);
      bf16x8 v1 = *(const bf16x8*)(Vl + (32 + r) * 256 + so);
      bf16x8 v2 = *(const bf16x8*)(Vl + (64 + r) * 256 + so);
      bf16x8 v3 = *(const bf16x8*)(Vl + (96 + r) * 256 + so);
      o0 = MFMA32(Ab, v0, o0);
      o1 = MFMA32(Ab, v1, o1);
      o2 = MFMA32(Ab, v2, o2);
      o3 = MFMA32(Ab, v3, o3);
    }
    __builtin_amdgcn_s_setprio(0);
  };

  auto COMPUTE = [&](const unsigned char* Kl, const unsigned char* Vl, int kv0) {
    // ---- swapped QK^T: S^T[kv][q] = K . Q^T, 4 independent chains ----
    f32x16 s0 = zero16(), s1 = zero16(), s2 = zero16(), s3 = zero16();
    __builtin_amdgcn_s_setprio(1);
#pragma unroll
    for (int c = 0; c < 8; ++c) {
      const int so = (((2 * c + hi) ^ (r & 7)) << 4);
      bf16x8 k0 = *(const bf16x8*)(Kl + r * 256 + so);
      bf16x8 k1 = *(const bf16x8*)(Kl + (32 + r) * 256 + so);
      bf16x8 k2 = *(const bf16x8*)(Kl + (64 + r) * 256 + so);
      bf16x8 k3 = *(const bf16x8*)(Kl + (96 + r) * 256 + so);
      s0 = MFMA32(k0, qf[c], s0);
      s1 = MFMA32(k1, qf[c], s1);
      s2 = MFMA32(k2, qf[c], s2);
      s3 = MFMA32(k3, qf[c], s3);
    }
    __builtin_amdgcn_s_setprio(0);

    // ---- causal mask (diagonal/overhang tiles only) ----
    if (kv0 + 127 > wq0) {
#pragma unroll
      for (int rr = 0; rr < 16; ++rr) {
        const int R = (rr & 3) + ((rr >> 2) << 3) + (hi << 2);
        if (kv0 + R > qrow)      s0[rr] = -1e30f;
        if (kv0 + 32 + R > qrow) s1[rr] = -1e30f;
        if (kv0 + 64 + R > qrow) s2[rr] = -1e30f;
        if (kv0 + 96 + R > qrow) s3[rr] = -1e30f;
      }
    }

    // ---- online softmax (log2 domain), defer-max; tree-reduced max ----
    float mx[8];
#pragma unroll
    for (int rr = 0; rr < 8; ++rr) {
      const float a = fmaxf(s0[rr], s0[rr + 8]);
      const float c = fmaxf(s1[rr], s1[rr + 8]);
      const float d = fmaxf(s2[rr], s2[rr + 8]);
      const float e = fmaxf(s3[rr], s3[rr + 8]);
      mx[rr] = fmaxf(fmaxf(a, c), fmaxf(d, e));
    }
#pragma unroll
    for (int rr = 0; rr < 4; ++rr) mx[rr] = fmaxf(mx[rr], mx[rr + 4]);
    float mt = fmaxf(fmaxf(mx[0], mx[1]), fmaxf(mx[2], mx[3]));
    mt = fmaxf(mt, __shfl_xor(mt, 32));

    if (__any(mt > m + 6.0f)) {
      const float mn = fmaxf(m, mt);
      const float sc = fexp2(m - mn);
      m = mn;
      lsum *= sc;
#pragma unroll
      for (int rr = 0; rr < 16; ++rr) {
        const float srow = __shfl(sc, (rr & 3) + ((rr >> 2) << 3) + (hi << 2));
        o0[rr] *= srow; o1[rr] *= srow; o2[rr] *= srow; o3[rr] *= srow;
      }
    }

    // ---- P = exp2(S - m) -> bf16 A-frags -> PV, fused per 32-kv block ----
    PACKPV(Vl, s0, 0);
    PACKPV(Vl, s1, 2);
    PACKPV(Vl, s2, 4);
    PACKPV(Vl, s3, 6);
  };

  const int nt = (qt64 >> 1) + 1;   // number of 128-kv tiles (1..8)

  // Prologue: stage tile 0, launch loads for tile 1.
  ISSUE(0);
  WRITE(Kl0, Vl0);
  if (nt > 1) ISSUE(128);

  unsigned char *Kc = Kl0, *Vc = Vl0, *Kn = Kl1, *Vn = Vl1;
  for (int t = 0; t < nt; ++t) {
    __syncthreads();                 // tile t visible; prior reads of 'next' done
    COMPUTE(Kc, Vc, t << 7);
    if (t + 1 < nt) {
      WRITE(Kn, Vn);                 // regs issued one compute-phase ago
      if (t + 2 < nt) ISSUE((t + 2) << 7);
      unsigned char* tp;
      tp = Kc; Kc = Kn; Kn = tp;
      tp = Vc; Vc = Vn; Vn = tp;
    }
  }

  // ---- epilogue ----
  float lt = lsum + __shfl_xor(lsum, 32);
#pragma unroll
  for (int rr = 0; rr < 16; ++rr) {
    const int R = (rr & 3) + ((rr >> 2) << 3) + (hi << 2);
    const float li = __shfl(lt, R);
    const float inv = 1.0f / li;
    float* op = Og + (size_t)(b * S_ + wq0 + R) * QSTR + h * D + r;
    op[0]  = o0[rr] * inv;
    op[32] = o1[rr] * inv;
    op[64] = o2[rr] * inv;
    op[96] = o3[rr] * inv;
  }
}

extern "C" void kernel_launch(void* const* d_in, const int* in_sizes, int n_in,
                              void* d_out, int out_size, void* d_ws, size_t ws_size,
                              hipStream_t stream) {
  const float* Q = (const float*)d_in[0];
  const float* K = (const float*)d_in[1];
  const float* V = (const float*)d_in[2];
  float* O = (float*)d_out;
  fa_kernel<<<dim3(512), dim3(512), 0, stream>>>(Q, K, V, O);
}

// Round 9
// 60.719 us; speedup vs baseline: 1.4978x; 1.4978x over previous
//
#include <hip/hip_runtime.h>

typedef __attribute__((ext_vector_type(8))) short bf16x8;
typedef __attribute__((ext_vector_type(16))) float f32x16;
typedef __attribute__((ext_vector_type(4))) unsigned uint4v;
typedef __attribute__((ext_vector_type(2))) unsigned uint2v;

#define MFMA32(a, b, c) __builtin_amdgcn_mfma_f32_32x32x16_bf16((a), (b), (c), 0, 0, 0)

__device__ __forceinline__ unsigned pk2(float lo, float hi) {
  unsigned r;
  asm("v_cvt_pk_bf16_f32 %0, %1, %2" : "=v"(r) : "v"(lo), "v"(hi));
  return r;
}

__device__ __forceinline__ float fexp2(float x) {
  float y; asm("v_exp_f32 %0, %1" : "=v"(y) : "v"(x)); return y;
}

__device__ __forceinline__ f32x16 zero16() {
  f32x16 z;
#pragma unroll
  for (int i = 0; i < 16; ++i) z[i] = 0.0f;
  return z;
}

constexpr int S_ = 1024, D = 128;
constexpr int QSTR = 32 * 128;  // query/out row stride (floats)
constexpr int KSTR = 8 * 128;   // key/value row stride (floats)
// log2(e)/sqrt(128): scores computed directly in log2 domain
constexpr float QSCL = 0.12751741f;

// grid = 512, block = 512 (8 waves). bid -> (hkv, b, qt64), heavy-first —
// EXACTLY the proven 63.6us R4 mapping (R5/R6/R7 alternatives regressed;
// R8's KVBLK=128 spilled). R9 change: WAVE PHASE STAGGER. All waves leave
// each barrier in lockstep running MFMA-burst then VALU-burst; the 2 waves
// sharing a SIMD (wid, wid+4) collide in both phases. Within a barrier
// interval WRITE(next buf) and COMPUTE(cur buf) are independent, so wid>=4
// waves run WRITE->ISSUE->COMPUTE while wid<4 run COMPUTE->WRITE->ISSUE:
// each SIMD then has one wave feeding MFMA while the other does VALU/VMEM.
// Zero register / zero semantic cost (wave-uniform branch, barriers outside).
__global__ __launch_bounds__(512, 2) void fa_kernel(
    const float* __restrict__ Qg, const float* __restrict__ Kg,
    const float* __restrict__ Vg, float* __restrict__ Og) {
  const int bid  = blockIdx.x;
  const int hkv  = bid & 7;
  const int b    = (bid >> 3) & 3;
  const int qt64 = 15 - (bid >> 5);   // 0..15, heaviest dispatched first
  const int h4   = hkv << 2;

  const int tid  = threadIdx.x;
  const int wid  = tid >> 6;          // 0..7
  const int lane = tid & 63;
  const int r    = lane & 31;
  const int hi   = lane >> 5;

  const int g     = wid & 3;
  const int strip = wid >> 2;
  const int h     = h4 + g;
  const int wq0   = (qt64 << 6) + (strip << 5);
  const int qrow  = wq0 + r;

  // K: [64 kv][128 bf16] rows of 256B = 16 slots, slot ^= (row&7)
  // V: transposed [128 d][64 bf16] rows of 128B = 8 slots, slot ^= (d&7)
  __shared__ __align__(16) unsigned char Kl0[64 * 256];
  __shared__ __align__(16) unsigned char Vl0[128 * 128];
  __shared__ __align__(16) unsigned char Kl1[64 * 256];
  __shared__ __align__(16) unsigned char Vl1[128 * 128];

  // ---- Q fragments (pre-scaled into log2 domain) ----
  bf16x8 qf[8];
  {
    const float* qp = Qg + (size_t)(b * S_ + qrow) * QSTR + h * D;
#pragma unroll
    for (int c = 0; c < 8; ++c) {
      const float4* p4 = (const float4*)(qp + 16 * c + 8 * hi);
      float4 x = p4[0], y = p4[1];
      uint4v w = (uint4v){pk2(x.x * QSCL, x.y * QSCL), pk2(x.z * QSCL, x.w * QSCL),
                          pk2(y.x * QSCL, y.y * QSCL), pk2(y.z * QSCL, y.w * QSCL)};
      qf[c] = __builtin_bit_cast(bf16x8, w);
    }
  }

  // ---- prefetch registers + stage mapping (512 threads share one tile) ----
  const int kvrow = tid >> 3;            // K: 8 threads per kv row
  const int dbase = (tid & 7) << 4;      // 16 floats each
  const float* kbase = Kg + (size_t)(b * S_) * KSTR + hkv * D;
  const int vd   = tid & 127;            // V: d index 0..127
  const int vkvb = (tid >> 7) << 4;      // kv sub-block 0/16/32/48
  const float* vbase = Vg + (size_t)(b * S_) * KSTR + hkv * D;

  float4 kreg[4];
  float  vreg[16];

  auto ISSUE = [&](int kv0) {
    const float4* kp = (const float4*)(kbase + (size_t)(kv0 + kvrow) * KSTR + dbase);
#pragma unroll
    for (int j = 0; j < 4; ++j) kreg[j] = kp[j];
    const float* vp = vbase + (size_t)(kv0 + vkvb) * KSTR + vd;
#pragma unroll
    for (int kk = 0; kk < 16; ++kk) vreg[kk] = vp[kk * KSTR];
  };

  auto WRITE = [&](unsigned char* Kl, unsigned char* Vl) {
#pragma unroll
    for (int ss = 0; ss < 2; ++ss) {
      float4 x = kreg[2 * ss], y = kreg[2 * ss + 1];
      uint4v w = (uint4v){pk2(x.x, x.y), pk2(x.z, x.w), pk2(y.x, y.y), pk2(y.z, y.w)};
      const int slot = (dbase >> 3) + ss;   // 2*(tid&7)+ss -> 0..15
      *(uint4v*)(Kl + kvrow * 256 + ((slot ^ (kvrow & 7)) << 4)) = w;
    }
#pragma unroll
    for (int ss = 0; ss < 2; ++ss) {
      uint4v w = (uint4v){pk2(vreg[8 * ss + 0], vreg[8 * ss + 1]),
                          pk2(vreg[8 * ss + 2], vreg[8 * ss + 3]),
                          pk2(vreg[8 * ss + 4], vreg[8 * ss + 5]),
                          pk2(vreg[8 * ss + 6], vreg[8 * ss + 7])};
      const int slot = (vkvb >> 3) + ss;    // 2*(tid>>7)+ss -> 0..7
      *(uint4v*)(Vl + vd * 128 + ((slot ^ (vd & 7)) << 4)) = w;
    }
  };

  f32x16 o0 = zero16(), o1 = zero16(), o2 = zero16(), o3 = zero16();
  float m = -1e30f, lsum = 0.0f;

  auto COMPUTE = [&](const unsigned char* Kl, const unsigned char* Vl, int kv0) {
    // ---- swapped QK^T: S^T[kv][q] = K . Q^T ----
    f32x16 s0 = zero16(), s1 = zero16();
    __builtin_amdgcn_s_setprio(1);
#pragma unroll
    for (int c = 0; c < 8; ++c) {
      const int so = (((2 * c + hi) ^ (r & 7)) << 4);
      bf16x8 k0 = *(const bf16x8*)(Kl + r * 256 + so);
      bf16x8 k1 = *(const bf16x8*)(Kl + (32 + r) * 256 + so);
      s0 = MFMA32(k0, qf[c], s0);
      s1 = MFMA32(k1, qf[c], s1);
    }
    __builtin_amdgcn_s_setprio(0);

    // ---- causal mask (diagonal tiles only) ----
    if (kv0 + 63 > wq0) {
#pragma unroll
      for (int rr = 0; rr < 16; ++rr) {
        const int R = (rr & 3) + ((rr >> 2) << 3) + (hi << 2);
        if (kv0 + R > qrow)      s0[rr] = -1e30f;
        if (kv0 + 32 + R > qrow) s1[rr] = -1e30f;
      }
    }

    // ---- online softmax (log2 domain), defer-max; tree-reduced max ----
    float mx[8];
#pragma unroll
    for (int rr = 0; rr < 8; ++rr)
      mx[rr] = fmaxf(fmaxf(s0[rr], s0[rr + 8]), fmaxf(s1[rr], s1[rr + 8]));
#pragma unroll
    for (int rr = 0; rr < 4; ++rr) mx[rr] = fmaxf(mx[rr], mx[rr + 4]);
    float mt = fmaxf(fmaxf(mx[0], mx[1]), fmaxf(mx[2], mx[3]));
    mt = fmaxf(mt, __shfl_xor(mt, 32));

    if (__any(mt > m + 6.0f)) {
      const float mn = fmaxf(m, mt);
      const float sc = fexp2(m - mn);
      m = mn;
      lsum *= sc;
#pragma unroll
      for (int rr = 0; rr < 16; ++rr) {
        const float srow = __shfl(sc, (rr & 3) + ((rr >> 2) << 3) + (hi << 2));
        o0[rr] *= srow; o1[rr] *= srow; o2[rr] *= srow; o3[rr] *= srow;
      }
    }

    // ---- P = exp2(S - m) packed to bf16 in-register, permlane32_swap into
    //      PV A-fragments (no LDS round-trip) ----
    float ps0 = 0.0f, ps1 = 0.0f, ps2 = 0.0f, ps3 = 0.0f;
    bf16x8 A0, A1, A2, A3;
    {
      float p[16];
#pragma unroll
      for (int rr = 0; rr < 16; ++rr) { p[rr] = fexp2(s0[rr] - m); }
#pragma unroll
      for (int rr = 0; rr < 4; ++rr) {
        ps0 += p[4 * rr + 0]; ps1 += p[4 * rr + 1];
        ps2 += p[4 * rr + 2]; ps3 += p[4 * rr + 3];
      }
      unsigned d0 = pk2(p[0], p[1]),   d1 = pk2(p[2], p[3]);
      unsigned d2 = pk2(p[4], p[5]),   d3 = pk2(p[6], p[7]);
      unsigned d4 = pk2(p[8], p[9]),   d5 = pk2(p[10], p[11]);
      unsigned d6 = pk2(p[12], p[13]), d7 = pk2(p[14], p[15]);
      uint2v w02 = __builtin_amdgcn_permlane32_swap(d0, d2, false, false);
      uint2v w13 = __builtin_amdgcn_permlane32_swap(d1, d3, false, false);
      uint2v w46 = __builtin_amdgcn_permlane32_swap(d4, d6, false, false);
      uint2v w57 = __builtin_amdgcn_permlane32_swap(d5, d7, false, false);
      A0 = __builtin_bit_cast(bf16x8, (uint4v){w02[0], w13[0], w02[1], w13[1]});
      A1 = __builtin_bit_cast(bf16x8, (uint4v){w46[0], w57[0], w46[1], w57[1]});
    }
    {
      float p[16];
#pragma unroll
      for (int rr = 0; rr < 16; ++rr) { p[rr] = fexp2(s1[rr] - m); }
#pragma unroll
      for (int rr = 0; rr < 4; ++rr) {
        ps0 += p[4 * rr + 0]; ps1 += p[4 * rr + 1];
        ps2 += p[4 * rr + 2]; ps3 += p[4 * rr + 3];
      }
      unsigned d0 = pk2(p[0], p[1]),   d1 = pk2(p[2], p[3]);
      unsigned d2 = pk2(p[4], p[5]),   d3 = pk2(p[6], p[7]);
      unsigned d4 = pk2(p[8], p[9]),   d5 = pk2(p[10], p[11]);
      unsigned d6 = pk2(p[12], p[13]), d7 = pk2(p[14], p[15]);
      uint2v w02 = __builtin_amdgcn_permlane32_swap(d0, d2, false, false);
      uint2v w13 = __builtin_amdgcn_permlane32_swap(d1, d3, false, false);
      uint2v w46 = __builtin_amdgcn_permlane32_swap(d4, d6, false, false);
      uint2v w57 = __builtin_amdgcn_permlane32_swap(d5, d7, false, false);
      A2 = __builtin_bit_cast(bf16x8, (uint4v){w02[0], w13[0], w02[1], w13[1]});
      A3 = __builtin_bit_cast(bf16x8, (uint4v){w46[0], w57[0], w46[1], w57[1]});
    }
    lsum += (ps0 + ps1) + (ps2 + ps3);

    // ---- PV: O += P . V ----
    __builtin_amdgcn_s_setprio(1);
#pragma unroll
    for (int t = 0; t < 4; ++t) {
      const bf16x8 pf = (t == 0) ? A0 : (t == 1) ? A1 : (t == 2) ? A2 : A3;
      const int so = (((2 * t + hi) ^ (r & 7)) << 4);
      bf16x8 v0 = *(const bf16x8*)(Vl + r * 128 + so);
      bf16x8 v1 = *(const bf16x8*)(Vl + (32 + r) * 128 + so);
      bf16x8 v2 = *(const bf16x8*)(Vl + (64 + r) * 128 + so);
      bf16x8 v3 = *(const bf16x8*)(Vl + (96 + r) * 128 + so);
      o0 = MFMA32(pf, v0, o0);
      o1 = MFMA32(pf, v1, o1);
      o2 = MFMA32(pf, v2, o2);
      o3 = MFMA32(pf, v3, o3);
    }
    __builtin_amdgcn_s_setprio(0);
  };

  const int nt = qt64 + 1;   // number of 64-kv tiles (1..16)

  // Prologue: stage tile 0, launch loads for tile 1.
  ISSUE(0);
  WRITE(Kl0, Vl0);
  if (nt > 1) ISSUE(64);

  unsigned char *Kc = Kl0, *Vc = Vl0, *Kn = Kl1, *Vn = Vl1;
  for (int t = 0; t < nt; ++t) {
    __syncthreads();   // tile t visible; ALL waves' reads of 'next' buffer done
    if (wid < 4) {
      // compute-first half: MFMA burst while sibling wave does VALU/VMEM
      COMPUTE(Kc, Vc, t << 6);
      if (t + 1 < nt) {
        WRITE(Kn, Vn);
        if (t + 2 < nt) ISSUE((t + 2) << 6);
      }
    } else {
      // stage-first half (sibling on same SIMD is in its MFMA phase)
      if (t + 1 < nt) {
        WRITE(Kn, Vn);
        if (t + 2 < nt) ISSUE((t + 2) << 6);
      }
      COMPUTE(Kc, Vc, t << 6);
    }
    if (t + 1 < nt) {
      unsigned char* tp;
      tp = Kc; Kc = Kn; Kn = tp;
      tp = Vc; Vc = Vn; Vn = tp;
    }
  }

  // ---- epilogue ----
  float lt = lsum + __shfl_xor(lsum, 32);
#pragma unroll
  for (int rr = 0; rr < 16; ++rr) {
    const int R = (rr & 3) + ((rr >> 2) << 3) + (hi << 2);
    const float li = __shfl(lt, R);
    const float inv = 1.0f / li;
    float* op = Og + (size_t)(b * S_ + wq0 + R) * QSTR + h * D + r;
    op[0]  = o0[rr] * inv;
    op[32] = o1[rr] * inv;
    op[64] = o2[rr] * inv;
    op[96] = o3[rr] * inv;
  }
}

extern "C" void kernel_launch(void* const* d_in, const int* in_sizes, int n_in,
                              void* d_out, int out_size, void* d_ws, size_t ws_size,
                              hipStream_t stream) {
  const float* Q = (const float*)d_in[0];
  const float* K = (const float*)d_in[1];
  const float* V = (const float*)d_in[2];
  float* O = (float*)d_out;
  fa_kernel<<<dim3(512), dim3(512), 0, stream>>>(Q, K, V, O);
}